// Round 7
// baseline (109.922 us; speedup 1.0000x reference)
//
#include <hip/hip_runtime.h>

#define LAMBDA_COORD 5.0f
#define LAMBDA_NOOBJ 0.5f

constexpr int Bn = 64;       // batch
constexpr int An = 10647;    // anchors
constexpr int Cn = 9;        // classes
constexpr int Gn = 50;       // gt boxes
constexpr int PRED_ROW = 5 + Cn;        // 14 floats per anchor row
constexpr int S  = 12;                  // splits: 12*64=768 blocks = 3/CU exactly
constexpr int AC = (An + S - 1) / S;    // 888 anchors per split
constexpr int ACP = ((AC + 63) / 64) * 64;  // 896 (14 scan iters)
constexpr int NW  = 5;                  // waves per block (320 threads)
constexpr int GTW = 10;                 // GTs per wave: 5*10 = 50, single pass

// ws layout:
//   partials : Bn*Gn*S float2 (score, idx-as-bits)  = 307200 B
//   bcepart  : Bn*S floats                           = 3072 B

// Single pass over the LDS chunk: 5 waves x 10 GTs covers all 50 GTs with
// zero slot padding (round 6's 2-pass/GTW=7 shape did 56 slots in 2 scans).
// ~110 live VGPRs fits the 128 cap from (320,4).
__global__ __launch_bounds__(320, 4) void yolo_k1(
    const float* __restrict__ pred,     // [B, A, 14]
    const float* __restrict__ bboxes,   // [B, G, 4]
    float2* __restrict__ partials,      // [B, G, S]
    float* __restrict__ bcepart)        // [B, S]
{
    const int s = blockIdx.x;
    const int b = blockIdx.y;
    const int a0 = s * AC;
    const int n  = min(AC, An - a0);    // 888 (879 for last split)

    __shared__ float4 sbox[ACP];  // x1,y1,x2,y2
    __shared__ float  sap[ACP];   // area_p
    __shared__ float  sred[NW];

    const int tid  = threadIdx.x;
    const int wave = tid >> 6;
    const int lane = tid & 63;

    // ---- stage anchors into LDS: loads hoisted, wave-uniform tail guard ----
    const float* prow = pred + (size_t)b * An * PRED_ROW;
    float2 va[3], vb[3];
    float  vc[3];
    #pragma unroll
    for (int k = 0; k < 3; ++k) {
        int i = tid + k * 320;                        // k=2 & tid>=256 -> skip (wave 4)
        if (i < ACP) {
            int ild = min(i, n - 1);                  // clamped: load always valid
            const float* p = prow + (size_t)(a0 + ild) * PRED_ROW;
            va[k] = ((const float2*)p)[0];            // cx, cy  (56*a is 8B-aligned)
            vb[k] = ((const float2*)p)[1];            // w, h
            vc[k] = p[4];                             // conf
        }
    }
    float bce = 0.0f;
    #pragma unroll
    for (int k = 0; k < 3; ++k) {
        int i = tid + k * 320;
        if (i < ACP) {
            bool valid = (i < n);
            float hw = 0.5f * vb[k].x, hh = 0.5f * vb[k].y;
            float x1 = va[k].x - hw, x2 = va[k].x + hw;
            float y1 = va[k].y - hh, y2 = va[k].y + hh;
            // sentinel pad: inter always 0 -> never beats strict-> compare
            sbox[i] = valid ? make_float4(x1, y1, x2, y2)
                            : make_float4(1e30f, 1e30f, 1e30f, 1e30f);
            sap[i]  = valid ? (x2 - x1) * (y2 - y1) : 0.0f;
            if (valid) bce -= fmaxf(__logf(1.0f - vc[k]), -100.0f);   // bce0
        }
    }
    #pragma unroll
    for (int off = 32; off >= 1; off >>= 1) bce += __shfl_xor(bce, off, 64);
    if (lane == 0) sred[wave] = bce;

    // ---- per-wave GT tile: wave w owns GTs w*10 .. w*10+9 (all real) ----
    const int g0 = wave * GTW;
    float gx1[GTW], gy1[GTW], gx2[GTW], gy2[GTW], gc1[GTW];
    const float* bb = bboxes + (size_t)b * Gn * 4;
    #pragma unroll
    for (int j = 0; j < GTW; ++j) {
        int g = g0 + j;
        float b0 = bb[g * 4 + 0], b1 = bb[g * 4 + 1];
        float b2 = bb[g * 4 + 2], b3 = bb[g * 4 + 3];
        float gcx = 0.5f * (b0 + b2), gcy = 0.5f * (b1 + b3);
        float gw = b2 - b0, gh = b3 - b1;
        gx1[j] = gcx - gw * 0.5f; gx2[j] = gcx + gw * 0.5f;
        gy1[j] = gcy - gh * 0.5f; gy2[j] = gcy + gh * 0.5f;
        gc1[j] = (gx2[j] - gx1[j]) * (gy2[j] - gy1[j]) + 1e-16f;  // area_g + eps
    }

    float bn[GTW], bd[GTW];
    int   bidx[GTW];
    #pragma unroll
    for (int j = 0; j < GTW; ++j) { bn[j] = 0.0f; bd[j] = 1.0f; bidx[j] = 0; }

    __syncthreads();
    if (tid == 0) {
        float t = 0.0f;
        #pragma unroll
        for (int w = 0; w < NW; ++w) t += sred[w];
        bcepart[b * S + s] = t;
    }

    // ---- main scan: branch-free, 10 IoUs per anchor read, unroll 2 ----
    #pragma unroll 2
    for (int base = 0; base < ACP; base += 64) {
        int i = base + lane;
        float4 pb = sbox[i];
        float  ap = sap[i];
        int   idx = a0 + i;
        #pragma unroll
        for (int j = 0; j < GTW; ++j) {
            float iw = fminf(pb.z, gx2[j]) - fmaxf(pb.x, gx1[j]);
            float ih = fminf(pb.w, gy2[j]) - fmaxf(pb.y, gy1[j]);
            iw = fmaxf(iw, 0.0f);
            ih = fmaxf(ih, 0.0f);
            float inter = iw * ih;
            float apc   = ap + gc1[j];
            // argmax of inter/(ap+ag-inter) == argmax of inter/(ap+ag):
            // r -> r/(1+r) monotone; compare fractions by cross-multiply.
            bool take = inter * bd[j] > bn[j] * apc;   // strict >: first max wins
            bn[j]   = take ? inter : bn[j];
            bd[j]   = take ? apc   : bd[j];
            bidx[j] = take ? idx   : bidx[j];
        }
    }

    // ---- cross-lane argmax per GT, write partial ----
    #pragma unroll
    for (int j = 0; j < GTW; ++j) {
        float score = bn[j] * __builtin_amdgcn_rcpf(bd[j]);  // monotone in iou
        int   idx   = bidx[j];
        #pragma unroll
        for (int off = 1; off < 64; off <<= 1) {
            float os = __shfl_xor(score, off, 64);
            int   oi = __shfl_xor(idx, off, 64);
            if (os > score) { score = os; idx = oi; }
        }
        if (lane == 0)
            partials[((size_t)b * Gn + g0 + j) * S + s] =
                make_float2(score, __int_as_float(idx));
    }
}

// k2: one block per image, 64 lanes; lane g owns GT g. (64,1) removes the
// VGPR cap so the 12-partial fold + pred row issue as parallel loads.
// Final scalar reduce: atomicAdd into out (zeroed by a 4B memset up front).
__global__ __launch_bounds__(64, 1) void yolo_k2(
    const float* __restrict__ pred,
    const float* __restrict__ bboxes,
    const int*  __restrict__ classes,   // [B, G]
    const float2* __restrict__ partials,
    const float* __restrict__ bcepart,
    float* __restrict__ out)            // [1], pre-zeroed
{
    const int b = blockIdx.x;
    const int g = threadIdx.x;

    int cls = (g < Gn) ? classes[b * Gn + g] : -1;

    float tot0 = 0.0f;
    #pragma unroll
    for (int s = 0; s < S; ++s) tot0 += bcepart[b * S + s];  // broadcast loads

    float per_gt = 0.0f;
    int   validf = 0;
    if (g < Gn) {
        validf = (cls != -1) ? 1 : 0;

        const float2* pp = partials + ((size_t)b * Gn + g) * S;
        float2 c[S];
        #pragma unroll
        for (int s = 0; s < S; ++s) c[s] = pp[s];   // 12 parallel loads
        float best = -1.0f;
        int   bi = 0;
        #pragma unroll
        for (int s = 0; s < S; ++s)
            if (c[s].x > best) { best = c[s].x; bi = __float_as_int(c[s].y); }

        const float2* p2 = (const float2*)(pred + ((size_t)b * An + bi) * PRED_ROW);
        float2 r[7];
        #pragma unroll
        for (int q = 0; q < 7; ++q) r[q] = p2[q];   // 7 parallel loads (56 B row)
        float pcx = r[0].x, pcy = r[0].y, pw = r[1].x, ph = r[1].y, conf = r[2].x;

        const float* bbg = bboxes + ((size_t)b * Gn + g) * 4;
        float b0 = bbg[0], b1 = bbg[1], b2 = bbg[2], b3 = bbg[3];
        float gcx = 0.5f * (b0 + b2), gcy = 0.5f * (b1 + b3);
        float gw = b2 - b0, gh = b3 - b1;

        float dx = pcx - gcx, dy = pcy - gcy, dw = pw - gw, dh = ph - gh;
        float coord = LAMBDA_COORD * (dx * dx + dy * dy + dw * dw + dh * dh);

        float conf_obj = -fmaxf(__logf(conf), -100.0f);

        const float pcls[Cn] = { r[2].y, r[3].x, r[3].y, r[4].x, r[4].y,
                                 r[5].x, r[5].y, r[6].x, r[6].y };
        float clsl = 0.0f;
        #pragma unroll
        for (int c2 = 0; c2 < Cn; ++c2) {
            float pc = pcls[c2];
            float lp = fmaxf(__logf(pc), -100.0f);
            float ln = fmaxf(__logf(1.0f - pc), -100.0f);
            clsl -= (c2 == cls) ? lp : ln;
        }

        float bce0b = -fmaxf(__logf(1.0f - conf), -100.0f);
        float noobj = LAMBDA_NOOBJ * (tot0 - bce0b);

        per_gt = coord + conf_obj + clsl + noobj;
        if (!validf) per_gt = 0.0f;
    }

    float sum = per_gt;
    int   anyv = validf;
    #pragma unroll
    for (int off = 1; off < 64; off <<= 1) {
        sum  += __shfl_xor(sum, off, 64);
        anyv |= __shfl_xor(anyv, off, 64);
    }
    if (g == 0) {
        float pi = anyv ? sum : (LAMBDA_NOOBJ * tot0);
        atomicAdd(out, pi * (1.0f / (float)Bn));
    }
}

extern "C" void kernel_launch(void* const* d_in, const int* in_sizes, int n_in,
                              void* d_out, int out_size, void* d_ws, size_t ws_size,
                              hipStream_t stream) {
    const float* pred    = (const float*)d_in[0];
    const float* bboxes  = (const float*)d_in[1];
    const int*   classes = (const int*)d_in[2];
    float* out = (float*)d_out;

    char* ws = (char*)d_ws;
    float2* partials = (float2*)ws;
    float*  bcepart  = (float*)(ws + (size_t)Bn * Gn * S * sizeof(float2));

    hipMemsetAsync(out, 0, sizeof(float), stream);   // out is the accumulator
    yolo_k1<<<dim3(S, Bn), 320, 0, stream>>>(pred, bboxes, partials, bcepart);
    yolo_k2<<<Bn, 64, 0, stream>>>(pred, bboxes, classes, partials, bcepart, out);
}